// Round 1
// baseline (120.053 us; speedup 1.0000x reference)
//
#include <hip/hip_runtime.h>

// ---------------------------------------------------------------------------
// STFT loss on MI355X.
// Reference: stft(frame=1024-padded 256-tap hann, hop=128) of LAST batch row
// of input & target, mag = sqrt(max(re^2+im^2, 1e-8)),
// loss = mean(|log xm - log ym|) + mean(|xm - ym|), means over [4096, 513].
// ---------------------------------------------------------------------------

#define T_LEN     524288
#define N_FRAMES  4096
#define NBINS     513
#define WIN_OFF   384          // window nonzero at k in [384, 640)
#define JF        8            // frames per main block
#define MAIN_BLOCKS (N_FRAMES / JF)     // 512
#define NYQ_BLOCKS  (N_FRAMES / 256)    // 16 blocks for bin 512
#define EPSQ      1e-8f
#define INV_N     (1.0f / (4096.0f * 513.0f))

// ---- weight table: wt[m*513 + f] = (cos(theta)*win, sin(theta)*win) --------
__global__ void build_wtab(float2* __restrict__ wt) {
    const int i = blockIdx.x * 256 + threadIdx.x;
    if (i >= 256 * NBINS) return;
    const int m = i / NBINS;
    const int f = i - m * NBINS;
    // periodic hann, length 256
    const float win = 0.5f - 0.5f * cosf(2.4543692606170259e-2f * (float)m); // 2*pi/256
    // exact integer phase mod 1024 (matches reference)
    const int phase = ((WIN_OFF + m) * f) & 1023;
    const float theta = -6.1359231515425647e-3f * (float)phase;              // -2*pi/1024
    float s, c;
    sincosf(theta, &s, &c);
    wt[i] = make_float2(c * win, s * win);
}

// ---- main kernel -----------------------------------------------------------
__launch_bounds__(256)
__global__ void stft_loss_kernel(const float* __restrict__ x,
                                 const float* __restrict__ y,
                                 const float2* __restrict__ wt,
                                 float* __restrict__ out)
{
    const int tid = threadIdx.x;
    float sum = 0.0f;

    if (blockIdx.x < MAIN_BLOCKS) {
        // ------- bins 0..511, 8 frames per block, 2 bins per thread --------
        const int t0 = blockIdx.x * JF;
        const int S  = t0 * 128 + WIN_OFF;   // block-uniform sample base
        const int f0 = tid;
        const int f1 = tid + 256;

        float xr0[JF], xi0[JF], yr0[JF], yi0[JF];
        float xr1[JF], xi1[JF], yr1[JF], yi1[JF];
        #pragma unroll
        for (int j = 0; j < JF; ++j) {
            xr0[j] = xi0[j] = yr0[j] = yi0[j] = 0.0f;
            xr1[j] = xi1[j] = yr1[j] = yi1[j] = 0.0f;
        }

        const bool safe = (S + (JF - 1) * 128 + 255) < T_LEN;  // uniform
        if (safe) {
            #pragma unroll 4
            for (int m = 0; m < 256; ++m) {
                const float2 w0 = wt[m * NBINS + f0];
                const float2 w1 = wt[m * NBINS + f1];
                #pragma unroll
                for (int j = 0; j < JF; ++j) {
                    // block-uniform addresses -> scalar loads (s_load)
                    const float xs = x[S + j * 128 + m];
                    const float ys = y[S + j * 128 + m];
                    xr0[j] = fmaf(xs, w0.x, xr0[j]);
                    xi0[j] = fmaf(xs, w0.y, xi0[j]);
                    yr0[j] = fmaf(ys, w0.x, yr0[j]);
                    yi0[j] = fmaf(ys, w0.y, yi0[j]);
                    xr1[j] = fmaf(xs, w1.x, xr1[j]);
                    xi1[j] = fmaf(xs, w1.y, xi1[j]);
                    yr1[j] = fmaf(ys, w1.x, yr1[j]);
                    yi1[j] = fmaf(ys, w1.y, yi1[j]);
                }
            }
        } else {
            #pragma unroll 4
            for (int m = 0; m < 256; ++m) {
                const float2 w0 = wt[m * NBINS + f0];
                const float2 w1 = wt[m * NBINS + f1];
                #pragma unroll
                for (int j = 0; j < JF; ++j) {
                    const int idx = S + j * 128 + m;     // uniform
                    const float xs = (idx < T_LEN) ? x[idx] : 0.0f;
                    const float ys = (idx < T_LEN) ? y[idx] : 0.0f;
                    xr0[j] = fmaf(xs, w0.x, xr0[j]);
                    xi0[j] = fmaf(xs, w0.y, xi0[j]);
                    yr0[j] = fmaf(ys, w0.x, yr0[j]);
                    yi0[j] = fmaf(ys, w0.y, yi0[j]);
                    xr1[j] = fmaf(xs, w1.x, xr1[j]);
                    xi1[j] = fmaf(xs, w1.y, xi1[j]);
                    yr1[j] = fmaf(ys, w1.x, yr1[j]);
                    yi1[j] = fmaf(ys, w1.y, yi1[j]);
                }
            }
        }

        #pragma unroll
        for (int j = 0; j < JF; ++j) {
            float xm = sqrtf(fmaxf(xr0[j] * xr0[j] + xi0[j] * xi0[j], EPSQ));
            float ym = sqrtf(fmaxf(yr0[j] * yr0[j] + yi0[j] * yi0[j], EPSQ));
            sum += fabsf(__logf(xm) - __logf(ym)) + fabsf(xm - ym);
            xm = sqrtf(fmaxf(xr1[j] * xr1[j] + xi1[j] * xi1[j], EPSQ));
            ym = sqrtf(fmaxf(yr1[j] * yr1[j] + yi1[j] * yi1[j], EPSQ));
            sum += fabsf(__logf(xm) - __logf(ym)) + fabsf(xm - ym);
        }
    } else {
        // ------- bin 512 (Nyquist), one frame per thread --------------------
        const int t = (blockIdx.x - MAIN_BLOCKS) * 256 + tid;   // 0..4095
        const int base = t * 128 + WIN_OFF;
        float xr = 0.f, xi = 0.f, yr = 0.f, yi = 0.f;
        #pragma unroll 4
        for (int m = 0; m < 256; ++m) {
            const float2 w = wt[m * NBINS + 512];   // uniform -> s_load
            const int idx = base + m;
            const float xv = (idx < T_LEN) ? x[idx] : 0.0f;
            const float yv = (idx < T_LEN) ? y[idx] : 0.0f;
            xr = fmaf(xv, w.x, xr);
            xi = fmaf(xv, w.y, xi);
            yr = fmaf(yv, w.x, yr);
            yi = fmaf(yv, w.y, yi);
        }
        const float xm = sqrtf(fmaxf(xr * xr + xi * xi, EPSQ));
        const float ym = sqrtf(fmaxf(yr * yr + yi * yi, EPSQ));
        sum = fabsf(__logf(xm) - __logf(ym)) + fabsf(xm - ym);
    }

    // ------- block reduction + global accumulate ----------------------------
    #pragma unroll
    for (int off = 32; off > 0; off >>= 1)
        sum += __shfl_down(sum, off, 64);

    __shared__ float red[4];
    if ((tid & 63) == 0) red[tid >> 6] = sum;
    __syncthreads();
    if (tid == 0) {
        const float bs = red[0] + red[1] + red[2] + red[3];
        atomicAdd(out, bs * INV_N);
    }
}

extern "C" void kernel_launch(void* const* d_in, const int* in_sizes, int n_in,
                              void* d_out, int out_size, void* d_ws, size_t ws_size,
                              hipStream_t stream) {
    const float* input  = (const float*)d_in[0];
    const float* target = (const float*)d_in[1];
    // reference indexes x_stft[-1]: only the LAST batch row matters
    const float* x = input  + (size_t)7 * T_LEN;
    const float* y = target + (size_t)7 * T_LEN;

    float2* wt = (float2*)d_ws;   // needs 256*513*8 = 1,050,624 bytes

    hipMemsetAsync(d_out, 0, sizeof(float), stream);

    const int wtab_elems = 256 * NBINS;
    build_wtab<<<(wtab_elems + 255) / 256, 256, 0, stream>>>(wt);

    stft_loss_kernel<<<MAIN_BLOCKS + NYQ_BLOCKS, 256, 0, stream>>>(
        x, y, wt, (float*)d_out);
}

// Round 2
// 60.974 us; speedup vs baseline: 1.9689x; 1.9689x over previous
//
#include <hip/hip_runtime.h>
#include <hip/hip_bf16.h>

// ---------------------------------------------------------------------------
// STFT loss via bf16 MFMA GEMM on MI355X (gfx950).
// C[frame][bin] re/im = sum_m x[frame*128+384+m] * win[m] * cos/sin(theta),
// theta = -2*pi*((384+m)*bin mod 1024)/1024.  Bins 0..511 via MFMA,
// bin 512 (Nyquist: sin=0, cos=(-1)^m) via a small f32 kernel.
// loss = mean(|log xm - log ym| + |xm - ym|) over [4096, 513].
// ---------------------------------------------------------------------------

#define T_LEN    524288
#define N_FRAMES 4096
#define WIN_OFF  384
#define EPSQ     1e-8f
#define INV_N    (1.0f / (4096.0f * 513.0f))

typedef __attribute__((ext_vector_type(8))) __bf16 bf16x8;
typedef __attribute__((ext_vector_type(4))) float  f32x4;

union bfbits { __hip_bfloat16 hb; __bf16 b; unsigned short u; };
static __device__ __forceinline__ __bf16 f2bf(float f) {
    bfbits t; t.hb = __float2bfloat16(f); return t.b;
}

// ---- weight tables (bf16, plain [bin][k] layout, 512x256 each) -------------
__global__ void build_wtab_bf16(__bf16* __restrict__ bre, __bf16* __restrict__ bim) {
    const int i = blockIdx.x * 256 + threadIdx.x;   // 0..131071
    const int bin = i >> 8;
    const int k = i & 255;
    const float win = 0.5f - 0.5f * cosf(2.4543692606170259e-2f * (float)k); // 2pi/256
    const int phase = ((WIN_OFF + k) * bin) & 1023;
    const float theta = -6.1359231515425647e-3f * (float)phase;              // -2pi/1024
    float s, c;
    sincosf(theta, &s, &c);
    bre[i] = f2bf(c * win);
    bim[i] = f2bf(s * win);
}

// ---- main MFMA kernel ------------------------------------------------------
// grid 512 = 64 frame-blocks x 8 bin-blocks; 256 threads (4 waves)
__launch_bounds__(256, 2)
__global__ void stft_mfma(const float* __restrict__ x, const float* __restrict__ y,
                          const __bf16* __restrict__ bre, const __bf16* __restrict__ bim,
                          float* __restrict__ out)
{
    // 4 tiles of [64 rows][128 k] bf16 = 16 KB each, 64 KB total
    __shared__ __bf16 lds[4 * 64 * 128];
    __bf16* const Ax = lds;
    __bf16* const Ay = lds + 8192;
    __bf16* const Br = lds + 16384;
    __bf16* const Bi = lds + 24576;

    const int tid  = threadIdx.x;
    const int mb   = blockIdx.x & 63;    // frame block
    const int nb   = blockIdx.x >> 6;    // bin block
    const int f0   = mb * 64;
    const int bin0 = nb * 64;
    const bool tail = (mb == 63);        // frames 4092..4095 read past T_LEN

    const int lane = tid & 63;
    const int wv   = tid >> 6;
    const int wr   = wv >> 1;            // wave row (0..1): frames
    const int wc   = wv & 1;             // wave col (0..1): bins
    const int lrow = lane & 15;
    const int lk   = lane >> 4;

    f32x4 axr[2][2], axi[2][2], ayr[2][2], ayi[2][2];
    #pragma unroll
    for (int mi = 0; mi < 2; ++mi)
        #pragma unroll
        for (int ni = 0; ni < 2; ++ni) {
            axr[mi][ni] = (f32x4)0.f; axi[mi][ni] = (f32x4)0.f;
            ayr[mi][ni] = (f32x4)0.f; ayi[mi][ni] = (f32x4)0.f;
        }

    #pragma unroll
    for (int h = 0; h < 2; ++h) {
        // ---------------- stage A (f32 -> bf16, swizzled ds_write_b128) -----
        #pragma unroll
        for (int w = 0; w < 4; ++w) {
            const int v   = tid + w * 256;      // 0..1023 chunk id
            const int row = v >> 4;             // 0..63
            const int c   = v & 15;             // chunk within row
            const int gbase = (f0 + row) * 128 + WIN_OFF + h * 128 + c * 8;
            bf16x8 vx, vy;
            if (!tail) {
                const float4 x0 = *(const float4*)(x + gbase);
                const float4 x1 = *(const float4*)(x + gbase + 4);
                const float4 y0 = *(const float4*)(y + gbase);
                const float4 y1 = *(const float4*)(y + gbase + 4);
                vx[0]=f2bf(x0.x); vx[1]=f2bf(x0.y); vx[2]=f2bf(x0.z); vx[3]=f2bf(x0.w);
                vx[4]=f2bf(x1.x); vx[5]=f2bf(x1.y); vx[6]=f2bf(x1.z); vx[7]=f2bf(x1.w);
                vy[0]=f2bf(y0.x); vy[1]=f2bf(y0.y); vy[2]=f2bf(y0.z); vy[3]=f2bf(y0.w);
                vy[4]=f2bf(y1.x); vy[5]=f2bf(y1.y); vy[6]=f2bf(y1.z); vy[7]=f2bf(y1.w);
            } else {
                #pragma unroll
                for (int j = 0; j < 8; ++j) {
                    const int idx = gbase + j;
                    vx[j] = f2bf(idx < T_LEN ? x[idx] : 0.f);
                    vy[j] = f2bf(idx < T_LEN ? y[idx] : 0.f);
                }
            }
            const int loff = row * 128 + ((c ^ (row & 7)) * 8);
            *(bf16x8*)(Ax + loff) = vx;
            *(bf16x8*)(Ay + loff) = vy;
        }
        // ---------------- stage B (bf16 table, swizzled ds_write_b128) ------
        #pragma unroll
        for (int w = 0; w < 4; ++w) {
            const int v   = tid + w * 256;      // 0..1023
            const int row = v >> 4;             // bin within tile
            const int c   = v & 15;
            const int src = (bin0 + row) * 256 + h * 128 + c * 8;
            const bf16x8 vr = *(const bf16x8*)(bre + src);
            const bf16x8 vi = *(const bf16x8*)(bim + src);
            const int loff = row * 128 + ((c ^ (row & 7)) * 8);
            *(bf16x8*)(Br + loff) = vr;
            *(bf16x8*)(Bi + loff) = vi;
        }
        __syncthreads();

        // ---------------- compute: 4 k-steps of 32 --------------------------
        #pragma unroll
        for (int ks = 0; ks < 4; ++ks) {
            const int cA = ks * 4 + lk;        // chunk index for this lane
            bf16x8 fax[2], fay[2], fbr[2], fbi[2];
            #pragma unroll
            for (int mi = 0; mi < 2; ++mi) {
                const int row = wr * 32 + mi * 16 + lrow;
                const int off = row * 128 + ((cA ^ (row & 7)) * 8);
                fax[mi] = *(const bf16x8*)(Ax + off);
                fay[mi] = *(const bf16x8*)(Ay + off);
            }
            #pragma unroll
            for (int ni = 0; ni < 2; ++ni) {
                const int row = wc * 32 + ni * 16 + lrow;
                const int off = row * 128 + ((cA ^ (row & 7)) * 8);
                fbr[ni] = *(const bf16x8*)(Br + off);
                fbi[ni] = *(const bf16x8*)(Bi + off);
            }
            #pragma unroll
            for (int mi = 0; mi < 2; ++mi)
                #pragma unroll
                for (int ni = 0; ni < 2; ++ni) {
                    axr[mi][ni] = __builtin_amdgcn_mfma_f32_16x16x32_bf16(fax[mi], fbr[ni], axr[mi][ni], 0, 0, 0);
                    axi[mi][ni] = __builtin_amdgcn_mfma_f32_16x16x32_bf16(fax[mi], fbi[ni], axi[mi][ni], 0, 0, 0);
                    ayr[mi][ni] = __builtin_amdgcn_mfma_f32_16x16x32_bf16(fay[mi], fbr[ni], ayr[mi][ni], 0, 0, 0);
                    ayi[mi][ni] = __builtin_amdgcn_mfma_f32_16x16x32_bf16(fay[mi], fbi[ni], ayi[mi][ni], 0, 0, 0);
                }
        }
        __syncthreads();
    }

    // ---------------- epilogue: loss, reduce, atomic ------------------------
    float sum = 0.f;
    #pragma unroll
    for (int mi = 0; mi < 2; ++mi)
        #pragma unroll
        for (int ni = 0; ni < 2; ++ni)
            #pragma unroll
            for (int r = 0; r < 4; ++r) {
                const float xr = axr[mi][ni][r], xi = axi[mi][ni][r];
                const float yr = ayr[mi][ni][r], yi = ayi[mi][ni][r];
                const float xm = sqrtf(fmaxf(xr * xr + xi * xi, EPSQ));
                const float ym = sqrtf(fmaxf(yr * yr + yi * yi, EPSQ));
                sum += fabsf(__logf(xm) - __logf(ym)) + fabsf(xm - ym);
            }

    #pragma unroll
    for (int off = 32; off > 0; off >>= 1)
        sum += __shfl_down(sum, off, 64);

    __shared__ float red[4];
    if (lane == 0) red[wv] = sum;
    __syncthreads();
    if (tid == 0)
        atomicAdd(out, (red[0] + red[1] + red[2] + red[3]) * INV_N);
}

// ---- Nyquist bin 512: re = sum win[m]*(-1)^m * x, im = 0 -------------------
// 128 blocks x 256 threads; 8 threads per frame (32 taps each)
__global__ void nyq_kernel(const float* __restrict__ x, const float* __restrict__ y,
                           float* __restrict__ out)
{
    const int tid = threadIdx.x;
    const int g = blockIdx.x * 256 + tid;    // 0..32767
    const int frame = g >> 3;
    const int p = g & 7;
    const int base = frame * 128 + WIN_OFF + p * 32;

    float xr = 0.f, yr = 0.f;
    #pragma unroll
    for (int j = 0; j < 32; ++j) {
        const int m = p * 32 + j;
        const int idx = base + j;
        float win = 0.5f - 0.5f * cosf(2.4543692606170259e-2f * (float)m);
        const float w = (m & 1) ? -win : win;
        const float xv = (idx < T_LEN) ? x[idx] : 0.f;
        const float yv = (idx < T_LEN) ? y[idx] : 0.f;
        xr = fmaf(xv, w, xr);
        yr = fmaf(yv, w, yr);
    }
    // reduce over the 8 lanes of this frame (p = lane&7)
    xr += __shfl_xor(xr, 1, 64); xr += __shfl_xor(xr, 2, 64); xr += __shfl_xor(xr, 4, 64);
    yr += __shfl_xor(yr, 1, 64); yr += __shfl_xor(yr, 2, 64); yr += __shfl_xor(yr, 4, 64);

    float sum = 0.f;
    if (p == 0) {
        const float xm = sqrtf(fmaxf(xr * xr, EPSQ));
        const float ym = sqrtf(fmaxf(yr * yr, EPSQ));
        sum = fabsf(__logf(xm) - __logf(ym)) + fabsf(xm - ym);
    }
    #pragma unroll
    for (int off = 32; off > 0; off >>= 1)
        sum += __shfl_down(sum, off, 64);

    __shared__ float red[4];
    if ((tid & 63) == 0) red[tid >> 6] = sum;
    __syncthreads();
    if (tid == 0)
        atomicAdd(out, (red[0] + red[1] + red[2] + red[3]) * INV_N);
}

extern "C" void kernel_launch(void* const* d_in, const int* in_sizes, int n_in,
                              void* d_out, int out_size, void* d_ws, size_t ws_size,
                              hipStream_t stream) {
    const float* input  = (const float*)d_in[0];
    const float* target = (const float*)d_in[1];
    const float* x = input  + (size_t)7 * T_LEN;   // reference uses x_stft[-1]
    const float* y = target + (size_t)7 * T_LEN;

    __bf16* wsBre = (__bf16*)d_ws;                 // 512*256*2 B = 256 KB
    __bf16* wsBim = wsBre + 512 * 256;             // + 256 KB  (ws >= 1 MB)

    hipMemsetAsync(d_out, 0, sizeof(float), stream);
    build_wtab_bf16<<<512, 256, 0, stream>>>(wsBre, wsBim);
    stft_mfma<<<512, 256, 0, stream>>>(x, y, wsBre, wsBim, (float*)d_out);
    nyq_kernel<<<128, 256, 0, stream>>>(x, y, (float*)d_out);
}

// Round 3
// 60.498 us; speedup vs baseline: 1.9844x; 1.0079x over previous
//
#include <hip/hip_runtime.h>
#include <hip/hip_bf16.h>

// ---------------------------------------------------------------------------
// STFT loss via bf16 MFMA GEMM on MI355X (gfx950).
// C[frame][bin] re/im = sum_m x[frame*128+384+m] * win[m] * cos/sin(theta),
// theta = -2*pi*((384+m)*bin mod 1024)/1024.  Bins 0..511 via MFMA,
// bin 512 (Nyquist: sin~0, cos=(-1)^m) via a coalesced f32 kernel.
// loss = mean(|log xm - log ym| + |xm - ym|) over [4096, 513].
// ---------------------------------------------------------------------------

#define T_LEN    524288
#define N_FRAMES 4096
#define WIN_OFF  384
#define EPSQ     1e-8f
#define INV_N    (1.0f / (4096.0f * 513.0f))

typedef __attribute__((ext_vector_type(8))) __bf16 bf16x8;
typedef __attribute__((ext_vector_type(4))) float  f32x4;

union bfbits { __hip_bfloat16 hb; __bf16 b; unsigned short u; };
static __device__ __forceinline__ __bf16 f2bf(float f) {
    bfbits t; t.hb = __float2bfloat16(f); return t.b;
}

// ---- weight tables (bf16, plain [bin][k] layout, 512x256 each) -------------
__global__ void build_wtab_bf16(__bf16* __restrict__ bre, __bf16* __restrict__ bim) {
    const int i = blockIdx.x * 256 + threadIdx.x;   // 0..131071
    const int bin = i >> 8;
    const int k = i & 255;
    const float win = 0.5f - 0.5f * cosf(2.4543692606170259e-2f * (float)k); // 2pi/256
    const int phase = ((WIN_OFF + k) * bin) & 1023;
    const float theta = -6.1359231515425647e-3f * (float)phase;              // -2pi/1024
    float s, c;
    sincosf(theta, &s, &c);
    bre[i] = f2bf(c * win);
    bim[i] = f2bf(s * win);
}

// ---- main MFMA kernel ------------------------------------------------------
// grid 512 = 64 frame-blocks x 8 bin-blocks; 256 threads (4 waves)
__launch_bounds__(256, 2)
__global__ void stft_mfma(const float* __restrict__ x, const float* __restrict__ y,
                          const __bf16* __restrict__ bre, const __bf16* __restrict__ bim,
                          float* __restrict__ out)
{
    // 4 tiles of [64 rows][128 k] bf16 = 16 KB each, 64 KB total
    __shared__ __bf16 lds[4 * 64 * 128];
    __bf16* const Ax = lds;
    __bf16* const Ay = lds + 8192;
    __bf16* const Br = lds + 16384;
    __bf16* const Bi = lds + 24576;

    const int tid  = threadIdx.x;
    const int mb   = blockIdx.x & 63;    // frame block
    const int nb   = blockIdx.x >> 6;    // bin block
    const int f0   = mb * 64;
    const int bin0 = nb * 64;
    const bool tail = (mb == 63);        // frames 4092..4095 read past T_LEN

    const int lane = tid & 63;
    const int wv   = tid >> 6;
    const int wr   = wv >> 1;            // wave row (0..1): frames
    const int wc   = wv & 1;             // wave col (0..1): bins
    const int lrow = lane & 15;
    const int lk   = lane >> 4;

    f32x4 axr[2][2], axi[2][2], ayr[2][2], ayi[2][2];
    #pragma unroll
    for (int mi = 0; mi < 2; ++mi)
        #pragma unroll
        for (int ni = 0; ni < 2; ++ni) {
            axr[mi][ni] = (f32x4)0.f; axi[mi][ni] = (f32x4)0.f;
            ayr[mi][ni] = (f32x4)0.f; ayi[mi][ni] = (f32x4)0.f;
        }

    #pragma unroll
    for (int h = 0; h < 2; ++h) {
        // ---------------- stage A (f32 -> bf16, swizzled ds_write_b128) -----
        #pragma unroll
        for (int w = 0; w < 4; ++w) {
            const int v   = tid + w * 256;      // 0..1023 chunk id
            const int row = v >> 4;             // 0..63
            const int c   = v & 15;             // chunk within row
            const int gbase = (f0 + row) * 128 + WIN_OFF + h * 128 + c * 8;
            bf16x8 vx, vy;
            if (!tail) {
                const float4 x0 = *(const float4*)(x + gbase);
                const float4 x1 = *(const float4*)(x + gbase + 4);
                const float4 y0 = *(const float4*)(y + gbase);
                const float4 y1 = *(const float4*)(y + gbase + 4);
                vx[0]=f2bf(x0.x); vx[1]=f2bf(x0.y); vx[2]=f2bf(x0.z); vx[3]=f2bf(x0.w);
                vx[4]=f2bf(x1.x); vx[5]=f2bf(x1.y); vx[6]=f2bf(x1.z); vx[7]=f2bf(x1.w);
                vy[0]=f2bf(y0.x); vy[1]=f2bf(y0.y); vy[2]=f2bf(y0.z); vy[3]=f2bf(y0.w);
                vy[4]=f2bf(y1.x); vy[5]=f2bf(y1.y); vy[6]=f2bf(y1.z); vy[7]=f2bf(y1.w);
            } else {
                #pragma unroll
                for (int j = 0; j < 8; ++j) {
                    const int idx = gbase + j;
                    vx[j] = f2bf(idx < T_LEN ? x[idx] : 0.f);
                    vy[j] = f2bf(idx < T_LEN ? y[idx] : 0.f);
                }
            }
            const int loff = row * 128 + ((c ^ (row & 7)) * 8);
            *(bf16x8*)(Ax + loff) = vx;
            *(bf16x8*)(Ay + loff) = vy;
        }
        // ---------------- stage B (bf16 table, swizzled ds_write_b128) ------
        #pragma unroll
        for (int w = 0; w < 4; ++w) {
            const int v   = tid + w * 256;      // 0..1023
            const int row = v >> 4;             // bin within tile
            const int c   = v & 15;
            const int src = (bin0 + row) * 256 + h * 128 + c * 8;
            const bf16x8 vr = *(const bf16x8*)(bre + src);
            const bf16x8 vi = *(const bf16x8*)(bim + src);
            const int loff = row * 128 + ((c ^ (row & 7)) * 8);
            *(bf16x8*)(Br + loff) = vr;
            *(bf16x8*)(Bi + loff) = vi;
        }
        __syncthreads();

        // ---------------- compute: 4 k-steps of 32 --------------------------
        #pragma unroll
        for (int ks = 0; ks < 4; ++ks) {
            const int cA = ks * 4 + lk;        // chunk index for this lane
            bf16x8 fax[2], fay[2], fbr[2], fbi[2];
            #pragma unroll
            for (int mi = 0; mi < 2; ++mi) {
                const int row = wr * 32 + mi * 16 + lrow;
                const int off = row * 128 + ((cA ^ (row & 7)) * 8);
                fax[mi] = *(const bf16x8*)(Ax + off);
                fay[mi] = *(const bf16x8*)(Ay + off);
            }
            #pragma unroll
            for (int ni = 0; ni < 2; ++ni) {
                const int row = wc * 32 + ni * 16 + lrow;
                const int off = row * 128 + ((cA ^ (row & 7)) * 8);
                fbr[ni] = *(const bf16x8*)(Br + off);
                fbi[ni] = *(const bf16x8*)(Bi + off);
            }
            #pragma unroll
            for (int mi = 0; mi < 2; ++mi)
                #pragma unroll
                for (int ni = 0; ni < 2; ++ni) {
                    axr[mi][ni] = __builtin_amdgcn_mfma_f32_16x16x32_bf16(fax[mi], fbr[ni], axr[mi][ni], 0, 0, 0);
                    axi[mi][ni] = __builtin_amdgcn_mfma_f32_16x16x32_bf16(fax[mi], fbi[ni], axi[mi][ni], 0, 0, 0);
                    ayr[mi][ni] = __builtin_amdgcn_mfma_f32_16x16x32_bf16(fay[mi], fbr[ni], ayr[mi][ni], 0, 0, 0);
                    ayi[mi][ni] = __builtin_amdgcn_mfma_f32_16x16x32_bf16(fay[mi], fbi[ni], ayi[mi][ni], 0, 0, 0);
                }
        }
        __syncthreads();
    }

    // ---------------- epilogue: loss, reduce, atomic ------------------------
    float sum = 0.f;
    #pragma unroll
    for (int mi = 0; mi < 2; ++mi)
        #pragma unroll
        for (int ni = 0; ni < 2; ++ni)
            #pragma unroll
            for (int r = 0; r < 4; ++r) {
                const float xr = axr[mi][ni][r], xi = axi[mi][ni][r];
                const float yr = ayr[mi][ni][r], yi = ayi[mi][ni][r];
                const float xm = sqrtf(fmaxf(xr * xr + xi * xi, EPSQ));
                const float ym = sqrtf(fmaxf(yr * yr + yi * yi, EPSQ));
                sum += fabsf(__logf(xm) - __logf(ym)) + fabsf(xm - ym);
            }

    #pragma unroll
    for (int off = 32; off > 0; off >>= 1)
        sum += __shfl_down(sum, off, 64);

    __shared__ float red[4];
    if (lane == 0) red[wv] = sum;
    __syncthreads();
    if (tid == 0)
        atomicAdd(out, (red[0] + red[1] + red[2] + red[3]) * INV_N);
}

// ---- Nyquist bin 512: re = sum win[m]*(-1)^m * x, im = 0 -------------------
// One WAVE per frame: lane l reads float4 at base+4l -> fully coalesced.
// grid 1024 blocks x 256 threads (4 waves = 4 frames per block).
__launch_bounds__(256)
__global__ void nyq_kernel(const float* __restrict__ x, const float* __restrict__ y,
                           float* __restrict__ out)
{
    __shared__ float w[256];
    __shared__ float red[4];
    const int tid = threadIdx.x;

    // precompute win[m]*(-1)^m once per block (1 cosf per thread)
    {
        const float win = 0.5f - 0.5f * cosf(2.4543692606170259e-2f * (float)tid);
        w[tid] = (tid & 1) ? -win : win;
    }
    __syncthreads();

    const int wv    = tid >> 6;
    const int lane  = tid & 63;
    const int frame = blockIdx.x * 4 + wv;          // 0..4095
    const int base  = frame * 128 + WIN_OFF + lane * 4;

    const float4 wl = *(const float4*)(w + lane * 4);
    float xr, yr;
    if (frame < 4092) {                             // wave-uniform branch
        const float4 xv = *(const float4*)(x + base);
        const float4 yv = *(const float4*)(y + base);
        xr = xv.x * wl.x + xv.y * wl.y + xv.z * wl.z + xv.w * wl.w;
        yr = yv.x * wl.x + yv.y * wl.y + yv.z * wl.z + yv.w * wl.w;
    } else {                                        // tail: zero-pad past T_LEN
        xr = 0.f; yr = 0.f;
        #pragma unroll
        for (int j = 0; j < 4; ++j) {
            const int idx = base + j;
            const float wj = (j == 0) ? wl.x : (j == 1) ? wl.y : (j == 2) ? wl.z : wl.w;
            if (idx < T_LEN) {
                xr = fmaf(x[idx], wj, xr);
                yr = fmaf(y[idx], wj, yr);
            }
        }
    }

    // reduce across the 64-lane wave
    #pragma unroll
    for (int off = 32; off > 0; off >>= 1) {
        xr += __shfl_xor(xr, off, 64);
        yr += __shfl_xor(yr, off, 64);
    }

    float sum = 0.f;
    if (lane == 0) {
        const float xm = sqrtf(fmaxf(xr * xr, EPSQ));
        const float ym = sqrtf(fmaxf(yr * yr, EPSQ));
        sum = fabsf(__logf(xm) - __logf(ym)) + fabsf(xm - ym);
        red[wv] = sum;
    }
    __syncthreads();
    if (tid == 0)
        atomicAdd(out, (red[0] + red[1] + red[2] + red[3]) * INV_N);
}

extern "C" void kernel_launch(void* const* d_in, const int* in_sizes, int n_in,
                              void* d_out, int out_size, void* d_ws, size_t ws_size,
                              hipStream_t stream) {
    const float* input  = (const float*)d_in[0];
    const float* target = (const float*)d_in[1];
    const float* x = input  + (size_t)7 * T_LEN;   // reference uses x_stft[-1]
    const float* y = target + (size_t)7 * T_LEN;

    __bf16* wsBre = (__bf16*)d_ws;                 // 512*256*2 B = 256 KB
    __bf16* wsBim = wsBre + 512 * 256;             // + 256 KB  (ws >= 1 MB)

    hipMemsetAsync(d_out, 0, sizeof(float), stream);
    build_wtab_bf16<<<512, 256, 0, stream>>>(wsBre, wsBim);
    stft_mfma<<<512, 256, 0, stream>>>(x, y, wsBre, wsBim, (float*)d_out);
    nyq_kernel<<<1024, 256, 0, stream>>>(x, y, (float*)d_out);
}

// Round 4
// 47.810 us; speedup vs baseline: 2.5111x; 1.2654x over previous
//
#include <hip/hip_runtime.h>
#include <hip/hip_bf16.h>

// ---------------------------------------------------------------------------
// Fully fused STFT loss on MI355X (gfx950), single kernel.
// C[frame][bin] re/im = sum_m x[frame*128+384+m] * win[m] * cis(theta),
// theta = -2*pi*((384+m)*bin mod 1024)/1024, frames 4096, bins 0..512.
// Bins 0..511 via bf16 MFMA with in-kernel weight generation (complex
// rotation recurrence); bin 512 (Nyquist: cos=(-1)^m, sin~0) folded into
// the epilogue with coalesced f32 loads.
// loss = mean(|log xm - log ym| + |xm - ym|) over [4096, 513].
// ---------------------------------------------------------------------------

#define T_LEN    524288
#define WIN_OFF  384
#define EPSQ     1e-8f
#define INV_N    (1.0f / (4096.0f * 513.0f))
#define A2PI_1024 6.1359231515425647e-3f   // 2*pi/1024
#define A2PI_256  2.4543692606170259e-2f   // 2*pi/256

typedef __attribute__((ext_vector_type(8))) __bf16 bf16x8;
typedef __attribute__((ext_vector_type(4))) float  f32x4;

union bfbits { __hip_bfloat16 hb; __bf16 b; unsigned short u; };
static __device__ __forceinline__ __bf16 f2bf(float f) {
    bfbits t; t.hb = __float2bfloat16(f); return t.b;
}

// grid 512 = 64 frame-blocks x 8 bin-blocks; 256 threads (4 waves); LDS 64 KB
__launch_bounds__(256, 2)
__global__ void stft_fused(const float* __restrict__ x, const float* __restrict__ y,
                           float* __restrict__ out)
{
    __shared__ __bf16 lds[4 * 64 * 128];      // exactly 64 KB
    __bf16* const Ax = lds;
    __bf16* const Ay = lds + 8192;
    __bf16* const Br = lds + 16384;
    __bf16* const Bi = lds + 24576;

    const int tid  = threadIdx.x;
    const int mb   = blockIdx.x & 63;    // frame block
    const int nb   = blockIdx.x >> 6;    // bin block
    const int f0   = mb * 64;
    const int bin0 = nb * 64;
    const bool tail = (mb == 63);        // frames 4092..4095 read past T_LEN

    const int lane = tid & 63;
    const int wv   = tid >> 6;
    const int wr   = wv >> 1;            // wave row: frames
    const int wc   = wv & 1;             // wave col: bins
    const int lrow = lane & 15;
    const int lk   = lane >> 4;

    f32x4 axr[2][2], axi[2][2], ayr[2][2], ayi[2][2];
    #pragma unroll
    for (int mi = 0; mi < 2; ++mi)
        #pragma unroll
        for (int ni = 0; ni < 2; ++ni) {
            axr[mi][ni] = (f32x4)0.f; axi[mi][ni] = (f32x4)0.f;
            ayr[mi][ni] = (f32x4)0.f; ayi[mi][ni] = (f32x4)0.f;
        }

    #pragma unroll
    for (int h = 0; h < 2; ++h) {
        // ---------------- stage A (f32 -> bf16, swizzled ds_write_b128) -----
        #pragma unroll
        for (int w = 0; w < 4; ++w) {
            const int v   = tid + w * 256;      // 0..1023 chunk id
            const int row = v >> 4;             // 0..63
            const int c   = v & 15;             // chunk within row
            const int gbase = (f0 + row) * 128 + WIN_OFF + h * 128 + c * 8;
            bf16x8 vx, vy;
            if (!tail) {
                const float4 x0 = *(const float4*)(x + gbase);
                const float4 x1 = *(const float4*)(x + gbase + 4);
                const float4 y0 = *(const float4*)(y + gbase);
                const float4 y1 = *(const float4*)(y + gbase + 4);
                vx[0]=f2bf(x0.x); vx[1]=f2bf(x0.y); vx[2]=f2bf(x0.z); vx[3]=f2bf(x0.w);
                vx[4]=f2bf(x1.x); vx[5]=f2bf(x1.y); vx[6]=f2bf(x1.z); vx[7]=f2bf(x1.w);
                vy[0]=f2bf(y0.x); vy[1]=f2bf(y0.y); vy[2]=f2bf(y0.z); vy[3]=f2bf(y0.w);
                vy[4]=f2bf(y1.x); vy[5]=f2bf(y1.y); vy[6]=f2bf(y1.z); vy[7]=f2bf(y1.w);
            } else {
                #pragma unroll
                for (int j = 0; j < 8; ++j) {
                    const int idx = gbase + j;
                    vx[j] = f2bf(idx < T_LEN ? x[idx] : 0.f);
                    vy[j] = f2bf(idx < T_LEN ? y[idx] : 0.f);
                }
            }
            const int loff = row * 128 + ((c ^ (row & 7)) * 8);
            *(bf16x8*)(Ax + loff) = vx;
            *(bf16x8*)(Ay + loff) = vy;
        }

        // ---------------- generate B half in-kernel (rotation recurrence) ---
        {
            const int b   = tid >> 2;            // bin within tile, 0..63
            const int q   = tid & 3;             // 32-k segment, 0..3
            const int bin = bin0 + b;
            const int k0  = h * 128 + q * 32;    // global tap index start
            // cis(theta) at k0, exact integer phase mod 1024
            float c, s;
            {
                const int ph0 = ((WIN_OFF + k0) * bin) & 1023;
                sincosf(-A2PI_1024 * (float)ph0, &s, &c);
            }
            // per-k rotation: cis(-2*pi*bin/1024)
            float stc, sts;
            sincosf(-A2PI_1024 * (float)bin, &sts, &stc);
            // hann window via rotation: cos/sin(2*pi*k/256)
            float wcos, wsin;
            sincosf(A2PI_256 * (float)k0, &wsin, &wcos);
            const float WC = 0.99969881869620425f;   // cos(2*pi/256)
            const float WS = 0.02454122852291229f;   // sin(2*pi/256)

            #pragma unroll
            for (int cc = 0; cc < 4; ++cc) {
                bf16x8 vr, vi;
                #pragma unroll
                for (int j = 0; j < 8; ++j) {
                    const float win = 0.5f - 0.5f * wcos;
                    vr[j] = f2bf(win * c);
                    vi[j] = f2bf(win * s);
                    const float nc = c * stc - s * sts;
                    const float ns = s * stc + c * sts;
                    c = nc; s = ns;
                    const float nwc = wcos * WC - wsin * WS;
                    const float nws = wsin * WC + wcos * WS;
                    wcos = nwc; wsin = nws;
                }
                const int ch   = q * 4 + cc;         // chunk within half, 0..15
                const int loff = b * 128 + ((ch ^ (b & 7)) * 8);
                *(bf16x8*)(Br + loff) = vr;
                *(bf16x8*)(Bi + loff) = vi;
            }
        }
        __syncthreads();

        // ---------------- compute: 4 k-steps of 32 --------------------------
        #pragma unroll
        for (int ks = 0; ks < 4; ++ks) {
            const int cA = ks * 4 + lk;
            bf16x8 fax[2], fay[2], fbr[2], fbi[2];
            #pragma unroll
            for (int mi = 0; mi < 2; ++mi) {
                const int row = wr * 32 + mi * 16 + lrow;
                const int off = row * 128 + ((cA ^ (row & 7)) * 8);
                fax[mi] = *(const bf16x8*)(Ax + off);
                fay[mi] = *(const bf16x8*)(Ay + off);
            }
            #pragma unroll
            for (int ni = 0; ni < 2; ++ni) {
                const int row = wc * 32 + ni * 16 + lrow;
                const int off = row * 128 + ((cA ^ (row & 7)) * 8);
                fbr[ni] = *(const bf16x8*)(Br + off);
                fbi[ni] = *(const bf16x8*)(Bi + off);
            }
            #pragma unroll
            for (int mi = 0; mi < 2; ++mi)
                #pragma unroll
                for (int ni = 0; ni < 2; ++ni) {
                    axr[mi][ni] = __builtin_amdgcn_mfma_f32_16x16x32_bf16(fax[mi], fbr[ni], axr[mi][ni], 0, 0, 0);
                    axi[mi][ni] = __builtin_amdgcn_mfma_f32_16x16x32_bf16(fax[mi], fbi[ni], axi[mi][ni], 0, 0, 0);
                    ayr[mi][ni] = __builtin_amdgcn_mfma_f32_16x16x32_bf16(fay[mi], fbr[ni], ayr[mi][ni], 0, 0, 0);
                    ayi[mi][ni] = __builtin_amdgcn_mfma_f32_16x16x32_bf16(fay[mi], fbi[ni], ayi[mi][ni], 0, 0, 0);
                }
        }
        __syncthreads();
    }

    // ---------------- epilogue: MFMA-tile loss ------------------------------
    float sum = 0.f;
    #pragma unroll
    for (int mi = 0; mi < 2; ++mi)
        #pragma unroll
        for (int ni = 0; ni < 2; ++ni)
            #pragma unroll
            for (int r = 0; r < 4; ++r) {
                const float xr = axr[mi][ni][r], xi = axi[mi][ni][r];
                const float yr = ayr[mi][ni][r], yi = ayi[mi][ni][r];
                const float xm = sqrtf(fmaxf(xr * xr + xi * xi, EPSQ));
                const float ym = sqrtf(fmaxf(yr * yr + yi * yi, EPSQ));
                sum += fabsf(__logf(xm) - __logf(ym)) + fabsf(xm - ym);
            }

    // ---------------- Nyquist bin 512: 8 frames per block, 2 per wave -------
    {
        float w4[4];
        #pragma unroll
        for (int j = 0; j < 4; ++j) {
            const int m = lane * 4 + j;
            const float win = 0.5f - 0.5f * cosf(A2PI_256 * (float)m);
            w4[j] = (m & 1) ? -win : win;
        }
        #pragma unroll
        for (int e = 0; e < 2; ++e) {
            const int frame = blockIdx.x * 8 + wv * 2 + e;      // 0..4095
            const int base  = frame * 128 + WIN_OFF + lane * 4;
            float xr, yr;
            if (frame < 4092) {                                 // wave-uniform
                const float4 xv = *(const float4*)(x + base);
                const float4 yv = *(const float4*)(y + base);
                xr = xv.x * w4[0] + xv.y * w4[1] + xv.z * w4[2] + xv.w * w4[3];
                yr = yv.x * w4[0] + yv.y * w4[1] + yv.z * w4[2] + yv.w * w4[3];
            } else {                                            // zero-pad tail
                xr = 0.f; yr = 0.f;
                #pragma unroll
                for (int j = 0; j < 4; ++j) {
                    const int idx = base + j;
                    if (idx < T_LEN) {
                        xr = fmaf(x[idx], w4[j], xr);
                        yr = fmaf(y[idx], w4[j], yr);
                    }
                }
            }
            #pragma unroll
            for (int off = 32; off > 0; off >>= 1) {
                xr += __shfl_xor(xr, off, 64);
                yr += __shfl_xor(yr, off, 64);
            }
            if (lane == 0) {
                const float xm = sqrtf(fmaxf(xr * xr, EPSQ));
                const float ym = sqrtf(fmaxf(yr * yr, EPSQ));
                sum += fabsf(__logf(xm) - __logf(ym)) + fabsf(xm - ym);
            }
        }
    }

    // ---------------- block reduce + global atomic --------------------------
    #pragma unroll
    for (int off = 32; off > 0; off >>= 1)
        sum += __shfl_down(sum, off, 64);

    float* red = (float*)lds;                 // LDS reuse (all reads done)
    if (lane == 0) red[wv] = sum;
    __syncthreads();
    if (tid == 0)
        atomicAdd(out, (red[0] + red[1] + red[2] + red[3]) * INV_N);
}

extern "C" void kernel_launch(void* const* d_in, const int* in_sizes, int n_in,
                              void* d_out, int out_size, void* d_ws, size_t ws_size,
                              hipStream_t stream) {
    const float* input  = (const float*)d_in[0];
    const float* target = (const float*)d_in[1];
    const float* x = input  + (size_t)7 * T_LEN;   // reference uses x_stft[-1]
    const float* y = target + (size_t)7 * T_LEN;

    hipMemsetAsync(d_out, 0, sizeof(float), stream);
    stft_fused<<<512, 256, 0, stream>>>(x, y, (float*)d_out);
}

// Round 5
// 46.425 us; speedup vs baseline: 2.5859x; 1.0298x over previous
//
#include <hip/hip_runtime.h>
#include <hip/hip_bf16.h>

// ---------------------------------------------------------------------------
// Fully fused STFT loss on MI355X (gfx950), single kernel.
// C[frame][bin] re/im = sum_m x[frame*128+384+m] * win[m] * cis(theta),
// theta = -2*pi*((384+m)*bin mod 1024)/1024, frames 4096, bins 0..512.
// Bins 0..511 via bf16 MFMA; B-operand (twiddle*window) generated in-kernel
// per tile with hardware v_sin/v_cos (no libm sincosf, no serial recurrence).
// Bin 512 (Nyquist: cos=(-1)^m, sin~0) folded into the epilogue.
// loss = mean(|log xm - log ym| + |xm - ym|) over [4096, 513].
// ---------------------------------------------------------------------------

#define T_LEN    524288
#define WIN_OFF  384
#define EPSQ     1e-8f
#define INV_N    (1.0f / (4096.0f * 513.0f))
#define A2PI_1024 6.1359231515425647e-3f   // 2*pi/1024
#define A2PI_256  2.4543692606170259e-2f   // 2*pi/256

typedef __attribute__((ext_vector_type(8))) __bf16 bf16x8;
typedef __attribute__((ext_vector_type(4))) float  f32x4;

union bfbits { __hip_bfloat16 hb; __bf16 b; unsigned short u; };
static __device__ __forceinline__ __bf16 f2bf(float f) {
    bfbits t; t.hb = __float2bfloat16(f); return t.b;
}

// grid 512 = 64 frame-blocks x 8 bin-blocks; 256 threads (4 waves)
__launch_bounds__(256, 2)
__global__ void stft_fused(const float* __restrict__ x, const float* __restrict__ y,
                           float* __restrict__ out)
{
    __shared__ __bf16 lds[4 * 64 * 128];      // 64 KB: Ax, Ay, Br, Bi tiles
    __shared__ float  win_s[256];             // hann window table
    __shared__ float  red_s[4];
    __bf16* const Ax = lds;
    __bf16* const Ay = lds + 8192;
    __bf16* const Br = lds + 16384;
    __bf16* const Bi = lds + 24576;

    const int tid  = threadIdx.x;
    const int mb   = blockIdx.x & 63;    // frame block
    const int nb   = blockIdx.x >> 6;    // bin block
    const int f0   = mb * 64;
    const int bin0 = nb * 64;
    const bool tail = (mb == 63);        // frames 4092..4095 read past T_LEN

    const int lane = tid & 63;
    const int wv   = tid >> 6;
    const int wr   = wv >> 1;            // wave row: frames
    const int wc   = wv & 1;             // wave col: bins
    const int lrow = lane & 15;
    const int lk   = lane >> 4;

    // window table: win[m] = 0.5 - 0.5*cos(2*pi*m/256), one v_cos per thread
    win_s[tid] = 0.5f - 0.5f * __cosf(A2PI_256 * (float)tid);
    __syncthreads();

    f32x4 axr[2][2], axi[2][2], ayr[2][2], ayi[2][2];
    #pragma unroll
    for (int mi = 0; mi < 2; ++mi)
        #pragma unroll
        for (int ni = 0; ni < 2; ++ni) {
            axr[mi][ni] = (f32x4)0.f; axi[mi][ni] = (f32x4)0.f;
            ayr[mi][ni] = (f32x4)0.f; ayi[mi][ni] = (f32x4)0.f;
        }

    #pragma unroll
    for (int h = 0; h < 2; ++h) {
        // ---------------- stage A (f32 -> bf16, swizzled ds_write_b128) -----
        #pragma unroll
        for (int w = 0; w < 4; ++w) {
            const int v   = tid + w * 256;      // 0..1023 chunk id
            const int row = v >> 4;             // 0..63
            const int c   = v & 15;             // chunk within row
            const int gbase = (f0 + row) * 128 + WIN_OFF + h * 128 + c * 8;
            bf16x8 vx, vy;
            if (!tail) {
                const float4 x0 = *(const float4*)(x + gbase);
                const float4 x1 = *(const float4*)(x + gbase + 4);
                const float4 y0 = *(const float4*)(y + gbase);
                const float4 y1 = *(const float4*)(y + gbase + 4);
                vx[0]=f2bf(x0.x); vx[1]=f2bf(x0.y); vx[2]=f2bf(x0.z); vx[3]=f2bf(x0.w);
                vx[4]=f2bf(x1.x); vx[5]=f2bf(x1.y); vx[6]=f2bf(x1.z); vx[7]=f2bf(x1.w);
                vy[0]=f2bf(y0.x); vy[1]=f2bf(y0.y); vy[2]=f2bf(y0.z); vy[3]=f2bf(y0.w);
                vy[4]=f2bf(y1.x); vy[5]=f2bf(y1.y); vy[6]=f2bf(y1.z); vy[7]=f2bf(y1.w);
            } else {
                #pragma unroll
                for (int j = 0; j < 8; ++j) {
                    const int idx = gbase + j;
                    vx[j] = f2bf(idx < T_LEN ? x[idx] : 0.f);
                    vy[j] = f2bf(idx < T_LEN ? y[idx] : 0.f);
                }
            }
            const int loff = row * 128 + ((c ^ (row & 7)) * 8);
            *(bf16x8*)(Ax + loff) = vx;
            *(bf16x8*)(Ay + loff) = vy;
        }

        // ---------------- generate B half in-kernel (hw v_sin/v_cos) --------
        {
            const int b   = tid >> 2;            // bin within tile, 0..63
            const int q   = tid & 3;             // 32-tap segment, 0..3
            const int bin = bin0 + b;
            const int kb  = h * 128 + q * 32;
            #pragma unroll
            for (int cc = 0; cc < 4; ++cc) {
                bf16x8 vr, vi;
                #pragma unroll
                for (int j = 0; j < 8; ++j) {
                    const int k = kb + cc * 8 + j;
                    const int p = ((WIN_OFF + k) * bin) & 1023;   // u24 mul
                    const float th = -A2PI_1024 * (float)p;
                    float s, c;
                    __sincosf(th, &s, &c);                        // v_sin+v_cos
                    const float w = win_s[k & 255];               // 4-addr bcast
                    vr[j] = f2bf(w * c);
                    vi[j] = f2bf(w * s);
                }
                const int ch   = q * 4 + cc;         // chunk within half
                const int loff = b * 128 + ((ch ^ (b & 7)) * 8);
                *(bf16x8*)(Br + loff) = vr;
                *(bf16x8*)(Bi + loff) = vi;
            }
        }
        __syncthreads();

        // ---------------- compute: 4 k-steps of 32 --------------------------
        #pragma unroll
        for (int ks = 0; ks < 4; ++ks) {
            const int cA = ks * 4 + lk;
            bf16x8 fax[2], fay[2], fbr[2], fbi[2];
            #pragma unroll
            for (int mi = 0; mi < 2; ++mi) {
                const int row = wr * 32 + mi * 16 + lrow;
                const int off = row * 128 + ((cA ^ (row & 7)) * 8);
                fax[mi] = *(const bf16x8*)(Ax + off);
                fay[mi] = *(const bf16x8*)(Ay + off);
            }
            #pragma unroll
            for (int ni = 0; ni < 2; ++ni) {
                const int row = wc * 32 + ni * 16 + lrow;
                const int off = row * 128 + ((cA ^ (row & 7)) * 8);
                fbr[ni] = *(const bf16x8*)(Br + off);
                fbi[ni] = *(const bf16x8*)(Bi + off);
            }
            #pragma unroll
            for (int mi = 0; mi < 2; ++mi)
                #pragma unroll
                for (int ni = 0; ni < 2; ++ni) {
                    axr[mi][ni] = __builtin_amdgcn_mfma_f32_16x16x32_bf16(fax[mi], fbr[ni], axr[mi][ni], 0, 0, 0);
                    axi[mi][ni] = __builtin_amdgcn_mfma_f32_16x16x32_bf16(fax[mi], fbi[ni], axi[mi][ni], 0, 0, 0);
                    ayr[mi][ni] = __builtin_amdgcn_mfma_f32_16x16x32_bf16(fay[mi], fbr[ni], ayr[mi][ni], 0, 0, 0);
                    ayi[mi][ni] = __builtin_amdgcn_mfma_f32_16x16x32_bf16(fay[mi], fbi[ni], ayi[mi][ni], 0, 0, 0);
                }
        }
        __syncthreads();
    }

    // ---------------- epilogue: MFMA-tile loss ------------------------------
    float sum = 0.f;
    #pragma unroll
    for (int mi = 0; mi < 2; ++mi)
        #pragma unroll
        for (int ni = 0; ni < 2; ++ni)
            #pragma unroll
            for (int r = 0; r < 4; ++r) {
                const float xr = axr[mi][ni][r], xi = axi[mi][ni][r];
                const float yr = ayr[mi][ni][r], yi = ayi[mi][ni][r];
                const float xm = sqrtf(fmaxf(xr * xr + xi * xi, EPSQ));
                const float ym = sqrtf(fmaxf(yr * yr + yi * yi, EPSQ));
                sum += fabsf(__logf(xm) - __logf(ym)) + fabsf(xm - ym);
            }

    // ---------------- Nyquist bin 512: 8 frames per block, 2 per wave -------
    {
        float w4[4];
        #pragma unroll
        for (int j = 0; j < 4; ++j) {
            const int m = lane * 4 + j;
            const float win = win_s[m];
            w4[j] = (m & 1) ? -win : win;
        }
        #pragma unroll
        for (int e = 0; e < 2; ++e) {
            const int frame = blockIdx.x * 8 + wv * 2 + e;      // 0..4095
            const int base  = frame * 128 + WIN_OFF + lane * 4;
            float xr, yr;
            if (frame < 4092) {                                 // wave-uniform
                const float4 xv = *(const float4*)(x + base);
                const float4 yv = *(const float4*)(y + base);
                xr = xv.x * w4[0] + xv.y * w4[1] + xv.z * w4[2] + xv.w * w4[3];
                yr = yv.x * w4[0] + yv.y * w4[1] + yv.z * w4[2] + yv.w * w4[3];
            } else {                                            // zero-pad tail
                xr = 0.f; yr = 0.f;
                #pragma unroll
                for (int j = 0; j < 4; ++j) {
                    const int idx = base + j;
                    if (idx < T_LEN) {
                        xr = fmaf(x[idx], w4[j], xr);
                        yr = fmaf(y[idx], w4[j], yr);
                    }
                }
            }
            #pragma unroll
            for (int off = 32; off > 0; off >>= 1) {
                xr += __shfl_xor(xr, off, 64);
                yr += __shfl_xor(yr, off, 64);
            }
            if (lane == 0) {
                const float xm = sqrtf(fmaxf(xr * xr, EPSQ));
                const float ym = sqrtf(fmaxf(yr * yr, EPSQ));
                sum += fabsf(__logf(xm) - __logf(ym)) + fabsf(xm - ym);
            }
        }
    }

    // ---------------- block reduce + global atomic --------------------------
    #pragma unroll
    for (int off = 32; off > 0; off >>= 1)
        sum += __shfl_down(sum, off, 64);

    if (lane == 0) red_s[wv] = sum;
    __syncthreads();
    if (tid == 0)
        atomicAdd(out, (red_s[0] + red_s[1] + red_s[2] + red_s[3]) * INV_N);
}

extern "C" void kernel_launch(void* const* d_in, const int* in_sizes, int n_in,
                              void* d_out, int out_size, void* d_ws, size_t ws_size,
                              hipStream_t stream) {
    const float* input  = (const float*)d_in[0];
    const float* target = (const float*)d_in[1];
    const float* x = input  + (size_t)7 * T_LEN;   // reference uses x_stft[-1]
    const float* y = target + (size_t)7 * T_LEN;

    hipMemsetAsync(d_out, 0, sizeof(float), stream);
    stft_fused<<<512, 256, 0, stream>>>(x, y, (float*)d_out);
}

// Round 6
// 46.244 us; speedup vs baseline: 2.5961x; 1.0039x over previous
//
#include <hip/hip_runtime.h>
#include <hip/hip_bf16.h>

// ---------------------------------------------------------------------------
// STFT loss on MI355X (gfx950), 3-kernel graph, no fills.
//   k1 build_wtab_bf16: B tables (twiddle*hann, bf16) -> d_ws
//   k2 stft_mfma:       bins 0..511 via bf16 MFMA (B from global),
//                       bin 512 (Nyquist) fused in epilogue,
//                       per-block partial sums -> d_ws
//   k3 reduce_partials: 512 partials -> d_out (overwrite, no memset needed)
// loss = mean(|log xm - log ym| + |xm - ym|) over [4096 frames, 513 bins].
// ---------------------------------------------------------------------------

#define T_LEN    524288
#define WIN_OFF  384
#define EPSQ     1e-8f
#define INV_N    (1.0f / (4096.0f * 513.0f))
#define A2PI_1024 6.1359231515425647e-3f   // 2*pi/1024
#define A2PI_256  2.4543692606170259e-2f   // 2*pi/256
#define WS_PARTIAL_OFF (512 * 256 * 2 * 2) // bytes: bre+bim tables

typedef __attribute__((ext_vector_type(8))) __bf16 bf16x8;
typedef __attribute__((ext_vector_type(4))) float  f32x4;

union bfbits { __hip_bfloat16 hb; __bf16 b; unsigned short u; };
static __device__ __forceinline__ __bf16 f2bf(float f) {
    bfbits t; t.hb = __float2bfloat16(f); return t.b;
}

// ---- weight tables (bf16, plain [bin][k] layout, 512x256 each) -------------
__global__ void build_wtab_bf16(__bf16* __restrict__ bre, __bf16* __restrict__ bim) {
    const int i = blockIdx.x * 256 + threadIdx.x;   // 0..131071
    const int bin = i >> 8;
    const int k = i & 255;
    const float win = 0.5f - 0.5f * __cosf(A2PI_256 * (float)k);
    const int phase = ((WIN_OFF + k) * bin) & 1023;
    float s, c;
    __sincosf(-A2PI_1024 * (float)phase, &s, &c);
    bre[i] = f2bf(c * win);
    bim[i] = f2bf(s * win);
}

// ---- main MFMA kernel ------------------------------------------------------
// grid 512 = 64 frame-blocks x 8 bin-blocks; 256 threads (4 waves)
__launch_bounds__(256, 2)
__global__ void stft_mfma(const float* __restrict__ x, const float* __restrict__ y,
                          const __bf16* __restrict__ bre, const __bf16* __restrict__ bim,
                          float* __restrict__ partials)
{
    __shared__ __bf16 lds[4 * 64 * 128];      // 64 KB: Ax, Ay, Br, Bi
    __shared__ float  red_s[4];
    __bf16* const Ax = lds;
    __bf16* const Ay = lds + 8192;
    __bf16* const Br = lds + 16384;
    __bf16* const Bi = lds + 24576;

    const int tid  = threadIdx.x;
    const int mb   = blockIdx.x & 63;    // frame block
    const int nb   = blockIdx.x >> 6;    // bin block
    const int f0   = mb * 64;
    const int bin0 = nb * 64;
    const bool tail = (mb == 63);        // frames 4032..4095 (guarded path)

    const int lane = tid & 63;
    const int wv   = tid >> 6;
    const int wr   = wv >> 1;            // wave row: frames
    const int wc   = wv & 1;             // wave col: bins
    const int lrow = lane & 15;
    const int lk   = lane >> 4;

    f32x4 axr[2][2], axi[2][2], ayr[2][2], ayi[2][2];
    #pragma unroll
    for (int mi = 0; mi < 2; ++mi)
        #pragma unroll
        for (int ni = 0; ni < 2; ++ni) {
            axr[mi][ni] = (f32x4)0.f; axi[mi][ni] = (f32x4)0.f;
            ayr[mi][ni] = (f32x4)0.f; ayi[mi][ni] = (f32x4)0.f;
        }

    #pragma unroll
    for (int h = 0; h < 2; ++h) {
        // ---------------- stage A (f32 -> bf16, swizzled ds_write_b128) -----
        #pragma unroll
        for (int w = 0; w < 4; ++w) {
            const int v   = tid + w * 256;      // 0..1023 chunk id
            const int row = v >> 4;             // 0..63
            const int c   = v & 15;             // chunk within row
            const int gbase = (f0 + row) * 128 + WIN_OFF + h * 128 + c * 8;
            bf16x8 vx, vy;
            if (!tail) {
                const float4 x0 = *(const float4*)(x + gbase);
                const float4 x1 = *(const float4*)(x + gbase + 4);
                const float4 y0 = *(const float4*)(y + gbase);
                const float4 y1 = *(const float4*)(y + gbase + 4);
                vx[0]=f2bf(x0.x); vx[1]=f2bf(x0.y); vx[2]=f2bf(x0.z); vx[3]=f2bf(x0.w);
                vx[4]=f2bf(x1.x); vx[5]=f2bf(x1.y); vx[6]=f2bf(x1.z); vx[7]=f2bf(x1.w);
                vy[0]=f2bf(y0.x); vy[1]=f2bf(y0.y); vy[2]=f2bf(y0.z); vy[3]=f2bf(y0.w);
                vy[4]=f2bf(y1.x); vy[5]=f2bf(y1.y); vy[6]=f2bf(y1.z); vy[7]=f2bf(y1.w);
            } else {
                #pragma unroll
                for (int j = 0; j < 8; ++j) {
                    const int idx = gbase + j;
                    vx[j] = f2bf(idx < T_LEN ? x[idx] : 0.f);
                    vy[j] = f2bf(idx < T_LEN ? y[idx] : 0.f);
                }
            }
            const int loff = row * 128 + ((c ^ (row & 7)) * 8);
            *(bf16x8*)(Ax + loff) = vx;
            *(bf16x8*)(Ay + loff) = vy;
        }
        // ---------------- stage B (bf16 table, swizzled ds_write_b128) ------
        #pragma unroll
        for (int w = 0; w < 4; ++w) {
            const int v   = tid + w * 256;      // 0..1023
            const int row = v >> 4;             // bin within tile
            const int c   = v & 15;
            const int src = (bin0 + row) * 256 + h * 128 + c * 8;
            const bf16x8 vr = *(const bf16x8*)(bre + src);
            const bf16x8 vi = *(const bf16x8*)(bim + src);
            const int loff = row * 128 + ((c ^ (row & 7)) * 8);
            *(bf16x8*)(Br + loff) = vr;
            *(bf16x8*)(Bi + loff) = vi;
        }
        __syncthreads();

        // ---------------- compute: 4 k-steps of 32 --------------------------
        #pragma unroll
        for (int ks = 0; ks < 4; ++ks) {
            const int cA = ks * 4 + lk;
            bf16x8 fax[2], fay[2], fbr[2], fbi[2];
            #pragma unroll
            for (int mi = 0; mi < 2; ++mi) {
                const int row = wr * 32 + mi * 16 + lrow;
                const int off = row * 128 + ((cA ^ (row & 7)) * 8);
                fax[mi] = *(const bf16x8*)(Ax + off);
                fay[mi] = *(const bf16x8*)(Ay + off);
            }
            #pragma unroll
            for (int ni = 0; ni < 2; ++ni) {
                const int row = wc * 32 + ni * 16 + lrow;
                const int off = row * 128 + ((cA ^ (row & 7)) * 8);
                fbr[ni] = *(const bf16x8*)(Br + off);
                fbi[ni] = *(const bf16x8*)(Bi + off);
            }
            #pragma unroll
            for (int mi = 0; mi < 2; ++mi)
                #pragma unroll
                for (int ni = 0; ni < 2; ++ni) {
                    axr[mi][ni] = __builtin_amdgcn_mfma_f32_16x16x32_bf16(fax[mi], fbr[ni], axr[mi][ni], 0, 0, 0);
                    axi[mi][ni] = __builtin_amdgcn_mfma_f32_16x16x32_bf16(fax[mi], fbi[ni], axi[mi][ni], 0, 0, 0);
                    ayr[mi][ni] = __builtin_amdgcn_mfma_f32_16x16x32_bf16(fay[mi], fbr[ni], ayr[mi][ni], 0, 0, 0);
                    ayi[mi][ni] = __builtin_amdgcn_mfma_f32_16x16x32_bf16(fay[mi], fbi[ni], ayi[mi][ni], 0, 0, 0);
                }
        }
        __syncthreads();
    }

    // ---------------- epilogue: MFMA-tile loss ------------------------------
    float sum = 0.f;
    #pragma unroll
    for (int mi = 0; mi < 2; ++mi)
        #pragma unroll
        for (int ni = 0; ni < 2; ++ni)
            #pragma unroll
            for (int r = 0; r < 4; ++r) {
                const float xr = axr[mi][ni][r], xi = axi[mi][ni][r];
                const float yr = ayr[mi][ni][r], yi = ayi[mi][ni][r];
                const float xm = sqrtf(fmaxf(xr * xr + xi * xi, EPSQ));
                const float ym = sqrtf(fmaxf(yr * yr + yi * yi, EPSQ));
                sum += fabsf(__logf(xm) - __logf(ym)) + fabsf(xm - ym);
            }

    // ---------------- Nyquist bin 512: 8 frames per block, 2 per wave -------
    {
        float w4[4];
        #pragma unroll
        for (int j = 0; j < 4; ++j) {
            const int m = lane * 4 + j;
            const float win = 0.5f - 0.5f * __cosf(A2PI_256 * (float)m);
            w4[j] = (m & 1) ? -win : win;
        }
        #pragma unroll
        for (int e = 0; e < 2; ++e) {
            const int frame = blockIdx.x * 8 + wv * 2 + e;      // 0..4095
            const int base  = frame * 128 + WIN_OFF + lane * 4;
            float xr, yr;
            if (frame < 4092) {                                 // wave-uniform
                const float4 xv = *(const float4*)(x + base);
                const float4 yv = *(const float4*)(y + base);
                xr = xv.x * w4[0] + xv.y * w4[1] + xv.z * w4[2] + xv.w * w4[3];
                yr = yv.x * w4[0] + yv.y * w4[1] + yv.z * w4[2] + yv.w * w4[3];
            } else {                                            // zero-pad tail
                xr = 0.f; yr = 0.f;
                #pragma unroll
                for (int j = 0; j < 4; ++j) {
                    const int idx = base + j;
                    if (idx < T_LEN) {
                        xr = fmaf(x[idx], w4[j], xr);
                        yr = fmaf(y[idx], w4[j], yr);
                    }
                }
            }
            #pragma unroll
            for (int off = 32; off > 0; off >>= 1) {
                xr += __shfl_xor(xr, off, 64);
                yr += __shfl_xor(yr, off, 64);
            }
            if (lane == 0) {
                const float xm = sqrtf(fmaxf(xr * xr, EPSQ));
                const float ym = sqrtf(fmaxf(yr * yr, EPSQ));
                sum += fabsf(__logf(xm) - __logf(ym)) + fabsf(xm - ym);
            }
        }
    }

    // ---------------- block reduce -> per-block partial ---------------------
    #pragma unroll
    for (int off = 32; off > 0; off >>= 1)
        sum += __shfl_down(sum, off, 64);

    if (lane == 0) red_s[wv] = sum;
    __syncthreads();
    if (tid == 0)
        partials[blockIdx.x] = red_s[0] + red_s[1] + red_s[2] + red_s[3];
}

// ---- final reduction: 512 partials -> scalar (overwrites d_out) ------------
__global__ void reduce_partials(const float* __restrict__ partials,
                                float* __restrict__ out)
{
    const int tid = threadIdx.x;
    float s = partials[tid] + partials[tid + 256];
    #pragma unroll
    for (int off = 32; off > 0; off >>= 1)
        s += __shfl_down(s, off, 64);

    __shared__ float red[4];
    if ((tid & 63) == 0) red[tid >> 6] = s;
    __syncthreads();
    if (tid == 0)
        out[0] = (red[0] + red[1] + red[2] + red[3]) * INV_N;
}

extern "C" void kernel_launch(void* const* d_in, const int* in_sizes, int n_in,
                              void* d_out, int out_size, void* d_ws, size_t ws_size,
                              hipStream_t stream) {
    const float* input  = (const float*)d_in[0];
    const float* target = (const float*)d_in[1];
    const float* x = input  + (size_t)7 * T_LEN;   // reference uses x_stft[-1]
    const float* y = target + (size_t)7 * T_LEN;

    __bf16* wsBre = (__bf16*)d_ws;                         // 256 KB
    __bf16* wsBim = wsBre + 512 * 256;                     // 256 KB
    float*  wsPart = (float*)((char*)d_ws + WS_PARTIAL_OFF); // 512 floats

    build_wtab_bf16<<<512, 256, 0, stream>>>(wsBre, wsBim);
    stft_mfma<<<512, 256, 0, stream>>>(x, y, wsBre, wsBim, wsPart);
    reduce_partials<<<1, 256, 0, stream>>>(wsPart, (float*)d_out);
}

// Round 7
// 38.249 us; speedup vs baseline: 3.1387x; 1.2090x over previous
//
#include <hip/hip_runtime.h>
#include <hip/hip_bf16.h>

// ---------------------------------------------------------------------------
// STFT loss on MI355X (gfx950). 3 kernels, no LDS staging, no barriers in
// the hot loop (everything is L2-resident: 2x2MB signals + 0.5MB B-table).
//   k1 prep:      x,y -> zero-padded bf16 copies (ws) + B tables (ws)
//   k2 stft_main: bins 0..511 via 16x16x32 bf16 MFMA, fragments loaded
//                 DIRECTLY from global (L2-hot); Nyquist bin 512 fused in
//                 epilogue (f32 path); per-block partials -> ws
//   k3 reduce_partials: 1024 partials -> d_out (overwrite, no memset)
// loss = mean(|log xm - log ym| + |xm - ym|) over [4096 frames, 513 bins].
// ---------------------------------------------------------------------------

#define T_LEN    524288
#define WIN_OFF  384
#define EPSQ     1e-8f
#define INV_N    (1.0f / (4096.0f * 513.0f))
#define A2PI_1024 6.1359231515425647e-3f   // 2*pi/1024
#define A2PI_256  2.4543692606170259e-2f   // 2*pi/256
#define NPAD     525312                    // padded signal length (>= 524800)

typedef __attribute__((ext_vector_type(8))) __bf16 bf16x8;
typedef __attribute__((ext_vector_type(4))) float  f32x4;

union bfbits { __hip_bfloat16 hb; __bf16 b; unsigned short u; };
static __device__ __forceinline__ __bf16 f2bf(float f) {
    bfbits t; t.hb = __float2bfloat16(f); return t.b;
}

// ---- prep: signal bf16 conversion (zero-padded) + weight tables ------------
// grid 1026 x 256: blocks [0,257) -> xb, [257,514) -> yb, [514,1026) -> wtab
__global__ void prep(const float* __restrict__ x, const float* __restrict__ y,
                     __bf16* __restrict__ xb, __bf16* __restrict__ yb,
                     __bf16* __restrict__ bre, __bf16* __restrict__ bim)
{
    const int b   = blockIdx.x;
    const int tid = threadIdx.x;

    if (b < 514) {
        const float* src = (b < 257) ? x : y;
        __bf16*      dst = (b < 257) ? xb : yb;
        const int gid = ((b < 257) ? b : b - 257) * 256 + tid;  // 0..65791
        if (gid < NPAD / 8) {
            bf16x8 v;
            if (gid < T_LEN / 8) {                 // full in-bounds chunk
                const float4 a0 = *(const float4*)(src + gid * 8);
                const float4 a1 = *(const float4*)(src + gid * 8 + 4);
                v[0]=f2bf(a0.x); v[1]=f2bf(a0.y); v[2]=f2bf(a0.z); v[3]=f2bf(a0.w);
                v[4]=f2bf(a1.x); v[5]=f2bf(a1.y); v[6]=f2bf(a1.z); v[7]=f2bf(a1.w);
            } else {                               // zero pad
                #pragma unroll
                for (int j = 0; j < 8; ++j) v[j] = f2bf(0.f);
            }
            *(bf16x8*)(dst + gid * 8) = v;
        }
    } else {
        const int i = (b - 514) * 256 + tid;       // 0..131071
        const int bin = i >> 8;
        const int k = i & 255;
        const float win = 0.5f - 0.5f * __cosf(A2PI_256 * (float)k);
        const int phase = ((WIN_OFF + k) * bin) & 1023;
        float s, c;
        __sincosf(-A2PI_1024 * (float)phase, &s, &c);
        bre[i] = f2bf(c * win);
        bim[i] = f2bf(s * win);
    }
}

// ---- main MFMA kernel: no LDS staging, no barriers -------------------------
// grid 1024 = 128 frame-blocks x 8 bin-blocks; 256 threads = 4 waves.
// Block tile: 32 frames x 64 bins. Wave tile: 16 frames x 32 bins
// (wr = frame half, wc = bin half). 16 waves/CU resident.
__launch_bounds__(256, 4)
__global__ void stft_main(const __bf16* __restrict__ xb, const __bf16* __restrict__ yb,
                          const __bf16* __restrict__ bre, const __bf16* __restrict__ bim,
                          const float* __restrict__ x, const float* __restrict__ y,
                          float* __restrict__ partials)
{
    const int tid  = threadIdx.x;
    const int mb   = blockIdx.x & 127;   // frame block (32 frames)
    const int nb   = blockIdx.x >> 7;    // bin block (64 bins)
    const int f0   = mb * 32;
    const int bin0 = nb * 64;

    const int lane = tid & 63;
    const int wv   = tid >> 6;
    const int wr   = wv >> 1;            // frame half (16 frames)
    const int wc   = wv & 1;             // bin half (32 bins)
    const int lrow = lane & 15;
    const int lk   = lane >> 4;

    // per-lane base addresses (block-uniform + lane part)
    const int arow = f0 + wr * 16 + lrow;            // frame row
    const int abase = arow * 128 + WIN_OFF + lk * 8; // sample index base
    const int bbin0 = bin0 + wc * 32 + lrow;         // bin for ni=0
    const int bbase0 = bbin0 * 256 + lk * 8;
    const int bbase1 = bbase0 + 16 * 256;            // ni=1 (+16 bins)

    f32x4 axr[2], axi[2], ayr[2], ayi[2];
    #pragma unroll
    for (int ni = 0; ni < 2; ++ni) {
        axr[ni] = (f32x4)0.f; axi[ni] = (f32x4)0.f;
        ayr[ni] = (f32x4)0.f; ayi[ni] = (f32x4)0.f;
    }

    // 8 k-steps of 32 taps; all loads straight from global (L2-hot)
    #pragma unroll 2
    for (int kk = 0; kk < 8; ++kk) {
        const int ko = kk * 32;
        const bf16x8 fax = *(const bf16x8*)(xb + abase + ko);
        const bf16x8 fay = *(const bf16x8*)(yb + abase + ko);
        const bf16x8 fbr0 = *(const bf16x8*)(bre + bbase0 + ko);
        const bf16x8 fbi0 = *(const bf16x8*)(bim + bbase0 + ko);
        const bf16x8 fbr1 = *(const bf16x8*)(bre + bbase1 + ko);
        const bf16x8 fbi1 = *(const bf16x8*)(bim + bbase1 + ko);

        axr[0] = __builtin_amdgcn_mfma_f32_16x16x32_bf16(fax, fbr0, axr[0], 0, 0, 0);
        axi[0] = __builtin_amdgcn_mfma_f32_16x16x32_bf16(fax, fbi0, axi[0], 0, 0, 0);
        ayr[0] = __builtin_amdgcn_mfma_f32_16x16x32_bf16(fay, fbr0, ayr[0], 0, 0, 0);
        ayi[0] = __builtin_amdgcn_mfma_f32_16x16x32_bf16(fay, fbi0, ayi[0], 0, 0, 0);
        axr[1] = __builtin_amdgcn_mfma_f32_16x16x32_bf16(fax, fbr1, axr[1], 0, 0, 0);
        axi[1] = __builtin_amdgcn_mfma_f32_16x16x32_bf16(fax, fbi1, axi[1], 0, 0, 0);
        ayr[1] = __builtin_amdgcn_mfma_f32_16x16x32_bf16(fay, fbr1, ayr[1], 0, 0, 0);
        ayi[1] = __builtin_amdgcn_mfma_f32_16x16x32_bf16(fay, fbi1, ayi[1], 0, 0, 0);
    }

    // ---------------- epilogue: MFMA-tile loss ------------------------------
    float sum = 0.f;
    #pragma unroll
    for (int ni = 0; ni < 2; ++ni)
        #pragma unroll
        for (int r = 0; r < 4; ++r) {
            const float xr = axr[ni][r], xi = axi[ni][r];
            const float yr = ayr[ni][r], yi = ayi[ni][r];
            const float xm = sqrtf(fmaxf(xr * xr + xi * xi, EPSQ));
            const float ym = sqrtf(fmaxf(yr * yr + yi * yi, EPSQ));
            sum += fabsf(__logf(xm) - __logf(ym)) + fabsf(xm - ym);
        }

    // ---------------- Nyquist bin 512: 4 frames per block, 1 per wave -------
    {
        float w4[4];
        #pragma unroll
        for (int j = 0; j < 4; ++j) {
            const int m = lane * 4 + j;
            const float win = 0.5f - 0.5f * __cosf(A2PI_256 * (float)m);
            w4[j] = (m & 1) ? -win : win;
        }
        const int frame = blockIdx.x * 4 + wv;          // 0..4095
        const int base  = frame * 128 + WIN_OFF + lane * 4;
        float xr, yr;
        if (frame < 4092) {                             // wave-uniform branch
            const float4 xv = *(const float4*)(x + base);
            const float4 yv = *(const float4*)(y + base);
            xr = xv.x * w4[0] + xv.y * w4[1] + xv.z * w4[2] + xv.w * w4[3];
            yr = yv.x * w4[0] + yv.y * w4[1] + yv.z * w4[2] + yv.w * w4[3];
        } else {                                        // zero-pad tail
            xr = 0.f; yr = 0.f;
            #pragma unroll
            for (int j = 0; j < 4; ++j) {
                const int idx = base + j;
                if (idx < T_LEN) {
                    xr = fmaf(x[idx], w4[j], xr);
                    yr = fmaf(y[idx], w4[j], yr);
                }
            }
        }
        #pragma unroll
        for (int off = 32; off > 0; off >>= 1) {
            xr += __shfl_xor(xr, off, 64);
            yr += __shfl_xor(yr, off, 64);
        }
        if (lane == 0) {
            const float xm = sqrtf(fmaxf(xr * xr, EPSQ));
            const float ym = sqrtf(fmaxf(yr * yr, EPSQ));
            sum += fabsf(__logf(xm) - __logf(ym)) + fabsf(xm - ym);
        }
    }

    // ---------------- block reduce -> per-block partial ---------------------
    #pragma unroll
    for (int off = 32; off > 0; off >>= 1)
        sum += __shfl_down(sum, off, 64);

    __shared__ float red_s[4];
    if (lane == 0) red_s[wv] = sum;
    __syncthreads();
    if (tid == 0)
        partials[blockIdx.x] = red_s[0] + red_s[1] + red_s[2] + red_s[3];
}

// ---- final reduction: 1024 partials -> scalar (overwrites d_out) -----------
__global__ void reduce_partials(const float* __restrict__ partials,
                                float* __restrict__ out)
{
    const int tid = threadIdx.x;
    float s = partials[tid] + partials[tid + 256]
            + partials[tid + 512] + partials[tid + 768];
    #pragma unroll
    for (int off = 32; off > 0; off >>= 1)
        s += __shfl_down(s, off, 64);

    __shared__ float red[4];
    if ((tid & 63) == 0) red[tid >> 6] = s;
    __syncthreads();
    if (tid == 0)
        out[0] = (red[0] + red[1] + red[2] + red[3]) * INV_N;
}

extern "C" void kernel_launch(void* const* d_in, const int* in_sizes, int n_in,
                              void* d_out, int out_size, void* d_ws, size_t ws_size,
                              hipStream_t stream) {
    const float* input  = (const float*)d_in[0];
    const float* target = (const float*)d_in[1];
    const float* x = input  + (size_t)7 * T_LEN;   // reference uses x_stft[-1]
    const float* y = target + (size_t)7 * T_LEN;

    // ws layout (bytes): bre[256K] bim[256K] xb[1.0M] yb[1.0M] partials[4K]
    char* ws = (char*)d_ws;
    __bf16* wsBre  = (__bf16*)(ws);
    __bf16* wsBim  = (__bf16*)(ws + 262144);
    __bf16* wsXb   = (__bf16*)(ws + 524288);
    __bf16* wsYb   = (__bf16*)(ws + 524288 + 1050624);
    float*  wsPart = (float*) (ws + 524288 + 2101248);

    prep<<<1026, 256, 0, stream>>>(x, y, wsXb, wsYb, wsBre, wsBim);
    stft_main<<<1024, 256, 0, stream>>>(wsXb, wsYb, wsBre, wsBim, x, y, wsPart);
    reduce_partials<<<1, 256, 0, stream>>>(wsPart, (float*)d_out);
}

// Round 8
// 24.241 us; speedup vs baseline: 4.9525x; 1.5779x over previous
//
#include <hip/hip_runtime.h>
#include <hip/hip_bf16.h>

// ---------------------------------------------------------------------------
// STFT loss on MI355X (gfx950). 3 kernels; the hot MFMA kernel reads BOTH
// operands from ws in PRE-INTERLEAVED fragment order ([tile][kstep][lane][8])
// so every load is wave-uniform-base + lane*16B (perfectly coalesced, no
// 16-way scatter). No LDS staging, no barriers in the hot loop.
//   k1 prep:      A (x,y signals, bf16) + B (twiddle*hann, bf16) -> fragment
//                 order in ws
//   k2 stft_main: bins 0..511 via 16x16x32 bf16 MFMA; Nyquist bin 512 fused
//                 (f32, coalesced); per-block partials -> ws
//   k3 reduce_partials: 1024 partials -> d_out (overwrite, no memset)
// loss = mean(|log xm - log ym| + |xm - ym|) over [4096 frames, 513 bins].
// ---------------------------------------------------------------------------

#define T_LEN    524288
#define WIN_OFF  384
#define EPSQ     1e-8f
#define INV_N    (1.0f / (4096.0f * 513.0f))
#define A2PI_1024 6.1359231515425647e-3f   // 2*pi/1024
#define A2PI_256  2.4543692606170259e-2f   // 2*pi/256

typedef __attribute__((ext_vector_type(8))) __bf16 bf16x8;
typedef __attribute__((ext_vector_type(4))) float  f32x4;

union bfbits { __hip_bfloat16 hb; __bf16 b; unsigned short u; };
static __device__ __forceinline__ __bf16 f2bf(float f) {
    bfbits t; t.hb = __float2bfloat16(f); return t.b;
}

// ---------------------------------------------------------------------------
// prep: build fragment-ordered operands.
// A-layout per signal: chunk (ft,kk) = [ft*8+kk], 64 lanes x 8 bf16 (1KB).
//   lane l of chunk holds A[frame = ft*16 + (l&15)][tap = kk*32 + (l>>4)*8 + j]
// B-layout: chunk (bt,kk); lane l holds B[bin = bt*16 + (l&15)][same tap].
// Wave i: i in [0,4096) -> A (sig = i>>11, ft = (i>>3)&255, kk = i&7);
//         i in [4096,4352) -> B (bt = (i-4096)>>3, kk = (i-4096)&7).
// grid 1088 x 256.
// ---------------------------------------------------------------------------
__global__ void prep(const float* __restrict__ x, const float* __restrict__ y,
                     __bf16* __restrict__ xb, __bf16* __restrict__ yb,
                     __bf16* __restrict__ bre, __bf16* __restrict__ bim)
{
    const int tid  = threadIdx.x;
    const int lane = tid & 63;
    const int wid  = blockIdx.x * 4 + (tid >> 6);

    if (wid < 4096) {
        const int sig = wid >> 11;
        const int chunk = wid & 2047;            // ft*8 + kk
        const int ft = chunk >> 3;
        const int kk = chunk & 7;
        const float* src = sig ? y : x;
        __bf16*      dst = sig ? yb : xb;
        const int frame = ft * 16 + (lane & 15);
        const int base  = frame * 128 + WIN_OFF + kk * 32 + (lane >> 4) * 8;
        bf16x8 v;
        if (base + 7 < T_LEN) {
            const float4 a0 = *(const float4*)(src + base);
            const float4 a1 = *(const float4*)(src + base + 4);
            v[0]=f2bf(a0.x); v[1]=f2bf(a0.y); v[2]=f2bf(a0.z); v[3]=f2bf(a0.w);
            v[4]=f2bf(a1.x); v[5]=f2bf(a1.y); v[6]=f2bf(a1.z); v[7]=f2bf(a1.w);
        } else {
            #pragma unroll
            for (int j = 0; j < 8; ++j) {
                const int idx = base + j;
                v[j] = f2bf(idx < T_LEN ? src[idx] : 0.f);
            }
        }
        *(bf16x8*)(dst + (size_t)chunk * 512 + lane * 8) = v;
    } else if (wid < 4096 + 256) {
        const int i  = wid - 4096;               // bt*8 + kk
        const int bt = i >> 3;
        const int kk = i & 7;
        const int bin = bt * 16 + (lane & 15);
        const int k0  = kk * 32 + (lane >> 4) * 8;
        bf16x8 vr, vi;
        #pragma unroll
        for (int j = 0; j < 8; ++j) {
            const int k = k0 + j;
            const float win = 0.5f - 0.5f * __cosf(A2PI_256 * (float)k);
            const int phase = ((WIN_OFF + k) * bin) & 1023;
            float s, c;
            __sincosf(-A2PI_1024 * (float)phase, &s, &c);
            vr[j] = f2bf(c * win);
            vi[j] = f2bf(s * win);
        }
        const size_t off = (size_t)i * 512 + lane * 8;
        *(bf16x8*)(bre + off) = vr;
        *(bf16x8*)(bim + off) = vi;
    }
}

// ---------------------------------------------------------------------------
// main MFMA kernel: all hot-loop loads coalesced (base + lane*16B).
// grid 1024 = 128 frame-blocks x 8 bin-blocks; 256 threads = 4 waves.
// Block tile: 32 frames x 64 bins. Wave tile: 16 frames x 32 bins.
// ---------------------------------------------------------------------------
__launch_bounds__(256, 4)
__global__ void stft_main(const __bf16* __restrict__ xb, const __bf16* __restrict__ yb,
                          const __bf16* __restrict__ bre, const __bf16* __restrict__ bim,
                          const float* __restrict__ x, const float* __restrict__ y,
                          float* __restrict__ partials)
{
    const int tid  = threadIdx.x;
    const int mb   = blockIdx.x & 127;   // frame block (32 frames)
    const int nb   = blockIdx.x >> 7;    // bin block (64 bins)

    const int lane = tid & 63;
    const int wv   = tid >> 6;
    const int wr   = wv >> 1;            // frame half
    const int wc   = wv & 1;             // bin half

    const int ft  = mb * 2 + wr;         // frame tile (16 frames)
    const int bt0 = nb * 4 + wc * 2;     // bin tiles (16 bins each)

    // fragment-ordered base pointers: chunk stride = 512 elems (1KB)
    const __bf16* pax = xb  + (size_t)ft  * 4096 + lane * 8;   // ft*8 chunks
    const __bf16* pay = yb  + (size_t)ft  * 4096 + lane * 8;
    const __bf16* pr0 = bre + (size_t)bt0 * 4096 + lane * 8;
    const __bf16* pi0 = bim + (size_t)bt0 * 4096 + lane * 8;
    const __bf16* pr1 = pr0 + 4096;                            // bt0+1
    const __bf16* pi1 = pi0 + 4096;

    f32x4 axr[2], axi[2], ayr[2], ayi[2];
    #pragma unroll
    for (int ni = 0; ni < 2; ++ni) {
        axr[ni] = (f32x4)0.f; axi[ni] = (f32x4)0.f;
        ayr[ni] = (f32x4)0.f; ayi[ni] = (f32x4)0.f;
    }

    #pragma unroll 2
    for (int kk = 0; kk < 8; ++kk) {
        const int ko = kk * 512;
        const bf16x8 fax  = *(const bf16x8*)(pax + ko);
        const bf16x8 fay  = *(const bf16x8*)(pay + ko);
        const bf16x8 fbr0 = *(const bf16x8*)(pr0 + ko);
        const bf16x8 fbi0 = *(const bf16x8*)(pi0 + ko);
        const bf16x8 fbr1 = *(const bf16x8*)(pr1 + ko);
        const bf16x8 fbi1 = *(const bf16x8*)(pi1 + ko);

        axr[0] = __builtin_amdgcn_mfma_f32_16x16x32_bf16(fax, fbr0, axr[0], 0, 0, 0);
        axi[0] = __builtin_amdgcn_mfma_f32_16x16x32_bf16(fax, fbi0, axi[0], 0, 0, 0);
        ayr[0] = __builtin_amdgcn_mfma_f32_16x16x32_bf16(fay, fbr0, ayr[0], 0, 0, 0);
        ayi[0] = __builtin_amdgcn_mfma_f32_16x16x32_bf16(fay, fbi0, ayi[0], 0, 0, 0);
        axr[1] = __builtin_amdgcn_mfma_f32_16x16x32_bf16(fax, fbr1, axr[1], 0, 0, 0);
        axi[1] = __builtin_amdgcn_mfma_f32_16x16x32_bf16(fax, fbi1, axi[1], 0, 0, 0);
        ayr[1] = __builtin_amdgcn_mfma_f32_16x16x32_bf16(fay, fbr1, ayr[1], 0, 0, 0);
        ayi[1] = __builtin_amdgcn_mfma_f32_16x16x32_bf16(fay, fbi1, ayi[1], 0, 0, 0);
    }

    // ---------------- epilogue: MFMA-tile loss ------------------------------
    float sum = 0.f;
    #pragma unroll
    for (int ni = 0; ni < 2; ++ni)
        #pragma unroll
        for (int r = 0; r < 4; ++r) {
            const float xr = axr[ni][r], xi = axi[ni][r];
            const float yr = ayr[ni][r], yi = ayi[ni][r];
            const float xm = sqrtf(fmaxf(xr * xr + xi * xi, EPSQ));
            const float ym = sqrtf(fmaxf(yr * yr + yi * yi, EPSQ));
            sum += fabsf(__logf(xm) - __logf(ym)) + fabsf(xm - ym);
        }

    // ---------------- Nyquist bin 512: 4 frames per block, 1 per wave -------
    {
        float w4[4];
        #pragma unroll
        for (int j = 0; j < 4; ++j) {
            const int m = lane * 4 + j;
            const float win = 0.5f - 0.5f * __cosf(A2PI_256 * (float)m);
            w4[j] = (m & 1) ? -win : win;
        }
        const int frame = blockIdx.x * 4 + wv;          // 0..4095
        const int base  = frame * 128 + WIN_OFF + lane * 4;
        float xr, yr;
        if (frame < 4092) {                             // wave-uniform branch
            const float4 xv = *(const float4*)(x + base);
            const float4 yv = *(const float4*)(y + base);
            xr = xv.x * w4[0] + xv.y * w4[1] + xv.z * w4[2] + xv.w * w4[3];
            yr = yv.x * w4[0] + yv.y * w4[1] + yv.z * w4[2] + yv.w * w4[3];
        } else {                                        // zero-pad tail
            xr = 0.f; yr = 0.f;
            #pragma unroll
            for (int j = 0; j < 4; ++j) {
                const int idx = base + j;
                if (idx < T_LEN) {
                    xr = fmaf(x[idx], w4[j], xr);
                    yr = fmaf(y[idx], w4[j], yr);
                }
            }
        }
        #pragma unroll
        for (int off = 32; off > 0; off >>= 1) {
            xr += __shfl_xor(xr, off, 64);
            yr += __shfl_xor(yr, off, 64);
        }
        if (lane == 0) {
            const float xm = sqrtf(fmaxf(xr * xr, EPSQ));
            const float ym = sqrtf(fmaxf(yr * yr, EPSQ));
            sum += fabsf(__logf(xm) - __logf(ym)) + fabsf(xm - ym);
        }
    }

    // ---------------- block reduce -> per-block partial ---------------------
    #pragma unroll
    for (int off = 32; off > 0; off >>= 1)
        sum += __shfl_down(sum, off, 64);

    __shared__ float red_s[4];
    if (lane == 0) red_s[wv] = sum;
    __syncthreads();
    if (tid == 0)
        partials[blockIdx.x] = red_s[0] + red_s[1] + red_s[2] + red_s[3];
}

// ---- final reduction: 1024 partials -> scalar (overwrites d_out) -----------
__global__ void reduce_partials(const float* __restrict__ partials,
                                float* __restrict__ out)
{
    const int tid = threadIdx.x;
    float s = partials[tid] + partials[tid + 256]
            + partials[tid + 512] + partials[tid + 768];
    #pragma unroll
    for (int off = 32; off > 0; off >>= 1)
        s += __shfl_down(s, off, 64);

    __shared__ float red[4];
    if ((tid & 63) == 0) red[tid >> 6] = s;
    __syncthreads();
    if (tid == 0)
        out[0] = (red[0] + red[1] + red[2] + red[3]) * INV_N;
}

extern "C" void kernel_launch(void* const* d_in, const int* in_sizes, int n_in,
                              void* d_out, int out_size, void* d_ws, size_t ws_size,
                              hipStream_t stream) {
    const float* input  = (const float*)d_in[0];
    const float* target = (const float*)d_in[1];
    const float* x = input  + (size_t)7 * T_LEN;   // reference uses x_stft[-1]
    const float* y = target + (size_t)7 * T_LEN;

    // ws layout (bytes):
    //   bre[256K] bim[256K] xb[2M] yb[2M] partials[4K]
    char* ws = (char*)d_ws;
    __bf16* wsBre  = (__bf16*)(ws);
    __bf16* wsBim  = (__bf16*)(ws + 262144);
    __bf16* wsXb   = (__bf16*)(ws + 524288);
    __bf16* wsYb   = (__bf16*)(ws + 524288 + 2097152);
    float*  wsPart = (float*) (ws + 524288 + 4194304);

    prep<<<1088, 256, 0, stream>>>(x, y, wsXb, wsYb, wsBre, wsBim);
    stft_main<<<1024, 256, 0, stream>>>(wsXb, wsYb, wsBre, wsBim, x, y, wsPart);
    reduce_partials<<<1, 256, 0, stream>>>(wsPart, (float*)d_out);
}